// Round 2
// baseline (1712.936 us; speedup 1.0000x reference)
//
#include <hip/hip_runtime.h>
#include <hip/hip_bf16.h>

// Fused InverseResNet: h = x@Wi+bi; 4x{10x fixed-point y-(relu(xW1+b1)W2+b2)}; out = x@Wf+bf
// Round 2: inputs/outputs are FP32 (reference dtypes). Internal compute bf16 MFMA,
// fp32 accumulate. 64-row tile per WG, activations ping-pong in LDS (bf16),
// W1/W2 register-resident B-fragments (W2 negated to fold y-g into the MFMA),
// y carried in fp32 registers across blocks. 32x32x16 bf16 MFMA, 1 WG/CU.

#define B_TOTAL 65536
#define LATENT  128
#define HIDDEN  256
#define OUTD    128
#define NBLOCKS 4
#define NITER   10
#define MTILE   64
#define LDSP    264   // row stride (elems); 264*2B/16B = 33 (odd) -> good b128 bank spread

typedef unsigned short u16;
typedef u16    u16x8  __attribute__((ext_vector_type(8)));
typedef __bf16 bf16x8 __attribute__((ext_vector_type(8)));
typedef float  f32x16 __attribute__((ext_vector_type(16)));

__device__ inline f32x16 splat16(float v){
  f32x16 r;
#pragma unroll
  for (int i=0;i<16;i++) r[i]=v;
  return r;
}
__device__ inline u16 f2b(float f){
  __bf16 h = (__bf16)f;
  return __builtin_bit_cast(u16, h);
}

// B-operand fragment for v_mfma_f32_32x32x16_bf16 from row-major fp32 W (ldw cols).
// lane layout: n = col, k = krow0 + j (j=0..7). neg=true loads -W (exact sign flip).
__device__ inline bf16x8 load_wfrag_f(const float* __restrict__ W, int ldw, int krow0,
                                      int col, bool neg){
  bf16x8 r;
#pragma unroll
  for (int j=0;j<8;j++){
    float v = W[(size_t)(krow0+j)*ldw + col];
    r[j] = (__bf16)(neg ? -v : v);
  }
  return r;
}

#define MFMA(a,b,c) __builtin_amdgcn_mfma_f32_32x32x16_bf16(a,b,c,0,0,0)

__global__ __launch_bounds__(256, 1)
void irn_kernel(const float* __restrict__ x,
                const float* __restrict__ Winit, const float* __restrict__ binit,
                const float* __restrict__ Wg1,   const float* __restrict__ bg1,
                const float* __restrict__ Wg2,   const float* __restrict__ bg2,
                const float* __restrict__ Wfin,  const float* __restrict__ bfin,
                float* __restrict__ out)
{
  __shared__ u16 Xb[MTILE*LDSP];
  __shared__ u16 Hb[MTILE*LDSP];

  const int tid = threadIdx.x;
  const int wv  = tid >> 6;      // wave 0..3 -> 64-col N-slice
  const int ln  = tid & 63;
  const int lo  = ln & 31;       // m / n index within 32
  const int hi  = ln >> 5;       // k half-group
  const int row0 = blockIdx.x * MTILE;

  // ---- stage x tile [64 x 128] fp32 -> bf16 into Xb (coalesced float4) ----
  {
    const int r  = tid >> 2;          // 0..63
    const int c0 = (tid & 3) * 32;    // col chunk
    const float4* src = (const float4*)(x + (size_t)(row0 + r)*LATENT + c0);
    u16* dst = Xb + r*LDSP + c0;
#pragma unroll
    for (int i=0;i<8;i++){
      float4 v = src[i];
      u16x8* d8 = (u16x8*)(dst + i*4);     // write 4 at a time via scalar pack
      dst[i*4+0]=f2b(v.x); dst[i*4+1]=f2b(v.y);
      dst[i*4+2]=f2b(v.z); dst[i*4+3]=f2b(v.w);
      (void)d8;
    }
  }

  const int nb    = wv * 64;
  const int colB0 = nb + lo;
  const int colB1 = nb + 32 + lo;
  const int rowA0 = lo * LDSP + hi*8;          // A-frag base, mt=0 (elements)
  const int rowA1 = (32 + lo) * LDSP + hi*8;   // mt=1

  f32x16 yreg[2][2];

  __syncthreads();

  // ---- initial GEMM: h = x @ Winit + binit (K=128) ----
  {
    bf16x8 wf[8][2];
#pragma unroll
    for (int ks=0; ks<8; ks++){
      wf[ks][0] = load_wfrag_f(Winit, HIDDEN, ks*16 + hi*8, colB0, false);
      wf[ks][1] = load_wfrag_f(Winit, HIDDEN, ks*16 + hi*8, colB1, false);
    }
    const float bi0 = binit[colB0];
    const float bi1 = binit[colB1];
    f32x16 acc[2][2];
    acc[0][0]=splat16(bi0); acc[0][1]=splat16(bi1);
    acc[1][0]=splat16(bi0); acc[1][1]=splat16(bi1);
#pragma unroll
    for (int ks=0; ks<8; ks++){
      bf16x8 a0 = *(const bf16x8*)(Xb + rowA0 + ks*16);
      bf16x8 a1 = *(const bf16x8*)(Xb + rowA1 + ks*16);
      acc[0][0]=MFMA(a0, wf[ks][0], acc[0][0]);
      acc[0][1]=MFMA(a0, wf[ks][1], acc[0][1]);
      acc[1][0]=MFMA(a1, wf[ks][0], acc[1][0]);
      acc[1][1]=MFMA(a1, wf[ks][1], acc[1][1]);
    }
    __syncthreads();   // everyone done reading Xb before overwrite
#pragma unroll
    for (int mt=0; mt<2; mt++)
#pragma unroll
      for (int nt=0; nt<2; nt++){
        const int col = nb + nt*32 + lo;
#pragma unroll
        for (int r=0; r<16; r++){
          const int row = mt*32 + (r&3) + 8*(r>>2) + 4*hi;
          Xb[row*LDSP + col] = f2b(acc[mt][nt][r]);
        }
        yreg[mt][nt] = acc[mt][nt];  // y for block 0, full fp32
      }
    __syncthreads();
  }

  // ---- 4 blocks x 10 fixed-point iterations ----
#pragma unroll 1
  for (int b=0; b<NBLOCKS; b++){
    const float* W1 = Wg1 + (size_t)b*HIDDEN*HIDDEN;
    const float* W2 = Wg2 + (size_t)b*HIDDEN*HIDDEN;
    bf16x8 w1f[16][2], w2f[16][2];
#pragma unroll
    for (int ks=0; ks<16; ks++){
      w1f[ks][0] = load_wfrag_f(W1, HIDDEN, ks*16 + hi*8, colB0, false);
      w1f[ks][1] = load_wfrag_f(W1, HIDDEN, ks*16 + hi*8, colB1, false);
      w2f[ks][0] = load_wfrag_f(W2, HIDDEN, ks*16 + hi*8, colB0, true); // -W2
      w2f[ks][1] = load_wfrag_f(W2, HIDDEN, ks*16 + hi*8, colB1, true);
    }
    const float b10 = bg1[b*HIDDEN + colB0];
    const float b11 = bg1[b*HIDDEN + colB1];
    const float b20 = bg2[b*HIDDEN + colB0];
    const float b21 = bg2[b*HIDDEN + colB1];

#pragma unroll 1
    for (int it=0; it<NITER; it++){
      { // phase 1: H = relu(X @ W1 + b1)
        f32x16 acc[2][2];
        acc[0][0]=splat16(b10); acc[0][1]=splat16(b11);
        acc[1][0]=splat16(b10); acc[1][1]=splat16(b11);
#pragma unroll
        for (int ks=0; ks<16; ks++){
          bf16x8 a0 = *(const bf16x8*)(Xb + rowA0 + ks*16);
          bf16x8 a1 = *(const bf16x8*)(Xb + rowA1 + ks*16);
          acc[0][0]=MFMA(a0, w1f[ks][0], acc[0][0]);
          acc[0][1]=MFMA(a0, w1f[ks][1], acc[0][1]);
          acc[1][0]=MFMA(a1, w1f[ks][0], acc[1][0]);
          acc[1][1]=MFMA(a1, w1f[ks][1], acc[1][1]);
        }
#pragma unroll
        for (int mt=0; mt<2; mt++)
#pragma unroll
          for (int nt=0; nt<2; nt++){
            const int col = nb + nt*32 + lo;
#pragma unroll
            for (int r=0; r<16; r++){
              const int row = mt*32 + (r&3) + 8*(r>>2) + 4*hi;
              float v = acc[mt][nt][r];
              v = v > 0.f ? v : 0.f;
              Hb[row*LDSP + col] = f2b(v);
            }
          }
      }
      __syncthreads();
      { // phase 2: Xnew = (y - b2) + H @ (-W2)
        f32x16 acc[2][2];
        acc[0][0]=yreg[0][0]-b20; acc[0][1]=yreg[0][1]-b21;
        acc[1][0]=yreg[1][0]-b20; acc[1][1]=yreg[1][1]-b21;
#pragma unroll
        for (int ks=0; ks<16; ks++){
          bf16x8 a0 = *(const bf16x8*)(Hb + rowA0 + ks*16);
          bf16x8 a1 = *(const bf16x8*)(Hb + rowA1 + ks*16);
          acc[0][0]=MFMA(a0, w2f[ks][0], acc[0][0]);
          acc[0][1]=MFMA(a0, w2f[ks][1], acc[0][1]);
          acc[1][0]=MFMA(a1, w2f[ks][0], acc[1][0]);
          acc[1][1]=MFMA(a1, w2f[ks][1], acc[1][1]);
        }
#pragma unroll
        for (int mt=0; mt<2; mt++)
#pragma unroll
          for (int nt=0; nt<2; nt++){
            const int col = nb + nt*32 + lo;
#pragma unroll
            for (int r=0; r<16; r++){
              const int row = mt*32 + (r&3) + 8*(r>>2) + 4*hi;
              Xb[row*LDSP + col] = f2b(acc[mt][nt][r]);
            }
            if (it == NITER-1) yreg[mt][nt] = acc[mt][nt]; // block output -> next y
          }
      }
      __syncthreads();
    }
  }

  // ---- final GEMM: out = X @ Wfin + bfin (N=128 -> 32 cols/wave), fp32 out ----
  {
    const int colf = wv*32 + lo;
    bf16x8 wf[16];
#pragma unroll
    for (int ks=0; ks<16; ks++)
      wf[ks] = load_wfrag_f(Wfin, OUTD, ks*16 + hi*8, colf, false);
    const float bv = bfin[colf];
    f32x16 acc0 = splat16(bv), acc1 = splat16(bv);
#pragma unroll
    for (int ks=0; ks<16; ks++){
      bf16x8 a0 = *(const bf16x8*)(Xb + rowA0 + ks*16);
      bf16x8 a1 = *(const bf16x8*)(Xb + rowA1 + ks*16);
      acc0 = MFMA(a0, wf[ks], acc0);
      acc1 = MFMA(a1, wf[ks], acc1);
    }
#pragma unroll
    for (int r=0; r<16; r++){
      const int row = (r&3) + 8*(r>>2) + 4*hi;
      out[(size_t)(row0 + row)*OUTD + colf]      = acc0[r];
      out[(size_t)(row0 + 32 + row)*OUTD + colf] = acc1[r];
    }
  }
}

extern "C" void kernel_launch(void* const* d_in, const int* in_sizes, int n_in,
                              void* d_out, int out_size, void* d_ws, size_t ws_size,
                              hipStream_t stream) {
  (void)in_sizes; (void)n_in; (void)d_ws; (void)ws_size; (void)out_size;
  const float* x     = (const float*)d_in[0];
  const float* Winit = (const float*)d_in[1];
  const float* binit = (const float*)d_in[2];
  const float* Wg1   = (const float*)d_in[3];
  const float* bg1   = (const float*)d_in[4];
  const float* Wg2   = (const float*)d_in[5];
  const float* bg2   = (const float*)d_in[6];
  const float* Wfin  = (const float*)d_in[7];
  const float* bfin  = (const float*)d_in[8];
  float* out = (float*)d_out;
  irn_kernel<<<dim3(B_TOTAL/MTILE), dim3(256), 0, stream>>>(
      x, Winit, binit, Wg1, bg1, Wg2, bg2, Wfin, bfin, out);
}

// Round 3
// 1188.718 us; speedup vs baseline: 1.4410x; 1.4410x over previous
//
#include <hip/hip_runtime.h>
#include <hip/hip_bf16.h>

// Fused InverseResNet: h = x@Wi+bi; 4x{10x fixed-point y-(relu(xW1+b1)W2+b2)}; out = x@Wf+bf
// Round 3: fix R2's register-spill catastrophe (1.2 GB scratch traffic, VGPR capped at 256).
// 512 threads / 8 waves per WG, each wave owns a 32-col N-slice -> register weights
// w1f+w2f = 128 VGPRs (was 256). acc 32 + yreg 32 + temps ~ 230 VGPR total -> no spill,
// 2 waves/SIMD occupancy. Activations ping-pong in LDS (bf16), W2 negated to fold y-g
// into MFMA accumulate, y carried in fp32 regs across blocks. 32x32x16 bf16 MFMA.

#define B_TOTAL 65536
#define LATENT  128
#define HIDDEN  256
#define OUTD    128
#define NBLOCKS 4
#define NITER   10
#define MTILE   64
#define LDSP    264   // row stride (elems); 264*2B=528B rows, 16B-aligned for ds_read_b128

typedef unsigned short u16;
typedef __bf16 bf16x8 __attribute__((ext_vector_type(8)));
typedef float  f32x16 __attribute__((ext_vector_type(16)));

__device__ inline f32x16 splat16(float v){
  f32x16 r;
#pragma unroll
  for (int i=0;i<16;i++) r[i]=v;
  return r;
}
__device__ inline u16 f2b(float f){
  __bf16 h = (__bf16)f;
  return __builtin_bit_cast(u16, h);
}

// B-operand fragment for v_mfma_f32_32x32x16_bf16 from row-major fp32 W (ldw cols).
// lane layout: n = col, k = krow0 + j (j=0..7). neg=true loads -W (exact sign flip).
__device__ inline bf16x8 load_wfrag_f(const float* __restrict__ W, int ldw, int krow0,
                                      int col, bool neg){
  bf16x8 r;
#pragma unroll
  for (int j=0;j<8;j++){
    float v = W[(size_t)(krow0+j)*ldw + col];
    r[j] = (__bf16)(neg ? -v : v);
  }
  return r;
}

#define MFMA(a,b,c) __builtin_amdgcn_mfma_f32_32x32x16_bf16(a,b,c,0,0,0)

__global__ __launch_bounds__(512, 1)
void irn_kernel(const float* __restrict__ x,
                const float* __restrict__ Winit, const float* __restrict__ binit,
                const float* __restrict__ Wg1,   const float* __restrict__ bg1,
                const float* __restrict__ Wg2,   const float* __restrict__ bg2,
                const float* __restrict__ Wfin,  const float* __restrict__ bfin,
                float* __restrict__ out)
{
  __shared__ u16 Xb[MTILE*LDSP];
  __shared__ u16 Hb[MTILE*LDSP];

  const int tid = threadIdx.x;
  const int wv  = tid >> 6;      // wave 0..7 -> 32-col N-slice of HIDDEN
  const int ln  = tid & 63;
  const int lo  = ln & 31;       // m / n index within 32
  const int hi  = ln >> 5;       // k half-group
  const int row0 = blockIdx.x * MTILE;

  // ---- stage x tile [64 x 128] fp32 -> bf16 into Xb (coalesced float4) ----
  {
    const int r  = tid >> 3;          // 0..63
    const int c0 = (tid & 7) * 16;    // col chunk of 16
    const float4* src = (const float4*)(x + (size_t)(row0 + r)*LATENT + c0);
    u16* dst = Xb + r*LDSP + c0;
#pragma unroll
    for (int i=0;i<4;i++){
      float4 v = src[i];
      dst[i*4+0]=f2b(v.x); dst[i*4+1]=f2b(v.y);
      dst[i*4+2]=f2b(v.z); dst[i*4+3]=f2b(v.w);
    }
  }

  const int nb    = wv * 32;                   // this wave's N-slice base (HIDDEN dim)
  const int colB  = nb + lo;
  const int rowA0 = lo * LDSP + hi*8;          // A-frag base, mt=0 (elements)
  const int rowA1 = (32 + lo) * LDSP + hi*8;   // mt=1

  f32x16 yreg[2];

  __syncthreads();

  // ---- initial GEMM: h = x @ Winit + binit (K=128) ----
  {
    bf16x8 wf[8];
#pragma unroll
    for (int ks=0; ks<8; ks++)
      wf[ks] = load_wfrag_f(Winit, HIDDEN, ks*16 + hi*8, colB, false);
    const float bi = binit[colB];
    f32x16 acc[2];
    acc[0]=splat16(bi); acc[1]=splat16(bi);
#pragma unroll
    for (int ks=0; ks<8; ks++){
      bf16x8 a0 = *(const bf16x8*)(Xb + rowA0 + ks*16);
      bf16x8 a1 = *(const bf16x8*)(Xb + rowA1 + ks*16);
      acc[0]=MFMA(a0, wf[ks], acc[0]);
      acc[1]=MFMA(a1, wf[ks], acc[1]);
    }
    __syncthreads();   // everyone done reading Xb before overwrite
#pragma unroll
    for (int mt=0; mt<2; mt++){
#pragma unroll
      for (int r=0; r<16; r++){
        const int row = mt*32 + (r&3) + 8*(r>>2) + 4*hi;
        Xb[row*LDSP + colB] = f2b(acc[mt][r]);
      }
      yreg[mt] = acc[mt];  // y for block 0, full fp32
    }
    __syncthreads();
  }

  // ---- 4 blocks x 10 fixed-point iterations ----
#pragma unroll 1
  for (int b=0; b<NBLOCKS; b++){
    const float* W1 = Wg1 + (size_t)b*HIDDEN*HIDDEN;
    const float* W2 = Wg2 + (size_t)b*HIDDEN*HIDDEN;
    bf16x8 w1f[16], w2f[16];
#pragma unroll
    for (int ks=0; ks<16; ks++){
      w1f[ks] = load_wfrag_f(W1, HIDDEN, ks*16 + hi*8, colB, false);
      w2f[ks] = load_wfrag_f(W2, HIDDEN, ks*16 + hi*8, colB, true); // -W2
    }
    const float b1v = bg1[b*HIDDEN + colB];
    const float b2v = bg2[b*HIDDEN + colB];

#pragma unroll 1
    for (int it=0; it<NITER; it++){
      { // phase 1: H = relu(X @ W1 + b1)
        f32x16 acc[2];
        acc[0]=splat16(b1v); acc[1]=splat16(b1v);
#pragma unroll
        for (int ks=0; ks<16; ks++){
          bf16x8 a0 = *(const bf16x8*)(Xb + rowA0 + ks*16);
          bf16x8 a1 = *(const bf16x8*)(Xb + rowA1 + ks*16);
          acc[0]=MFMA(a0, w1f[ks], acc[0]);
          acc[1]=MFMA(a1, w1f[ks], acc[1]);
        }
#pragma unroll
        for (int mt=0; mt<2; mt++)
#pragma unroll
          for (int r=0; r<16; r++){
            const int row = mt*32 + (r&3) + 8*(r>>2) + 4*hi;
            float v = acc[mt][r];
            v = v > 0.f ? v : 0.f;
            Hb[row*LDSP + colB] = f2b(v);
          }
      }
      __syncthreads();
      { // phase 2: Xnew = (y - b2) + H @ (-W2)
        f32x16 acc[2];
        acc[0]=yreg[0]-b2v; acc[1]=yreg[1]-b2v;
#pragma unroll
        for (int ks=0; ks<16; ks++){
          bf16x8 a0 = *(const bf16x8*)(Hb + rowA0 + ks*16);
          bf16x8 a1 = *(const bf16x8*)(Hb + rowA1 + ks*16);
          acc[0]=MFMA(a0, w2f[ks], acc[0]);
          acc[1]=MFMA(a1, w2f[ks], acc[1]);
        }
#pragma unroll
        for (int mt=0; mt<2; mt++){
#pragma unroll
          for (int r=0; r<16; r++){
            const int row = mt*32 + (r&3) + 8*(r>>2) + 4*hi;
            Xb[row*LDSP + colB] = f2b(acc[mt][r]);
          }
          if (it == NITER-1) yreg[mt] = acc[mt]; // block output -> next y
        }
      }
      __syncthreads();
    }
  }

  // ---- final GEMM: out = X @ Wfin + bfin (N=128), fp32 out ----
  // 8 waves: wave w covers rows [(w>>2)*32, +32) x cols [(w&3)*32, +32)
  {
    const int mrow = (wv >> 2) * 32;
    const int colf = (wv & 3) * 32 + lo;
    const int rowAf = (mrow + lo) * LDSP + hi*8;
    bf16x8 wf[16];
#pragma unroll
    for (int ks=0; ks<16; ks++)
      wf[ks] = load_wfrag_f(Wfin, OUTD, ks*16 + hi*8, colf, false);
    const float bv = bfin[colf];
    f32x16 acc = splat16(bv);
#pragma unroll
    for (int ks=0; ks<16; ks++){
      bf16x8 a = *(const bf16x8*)(Xb + rowAf + ks*16);
      acc = MFMA(a, wf[ks], acc);
    }
#pragma unroll
    for (int r=0; r<16; r++){
      const int row = mrow + (r&3) + 8*(r>>2) + 4*hi;
      out[(size_t)(row0 + row)*OUTD + colf] = acc[r];
    }
  }
}

extern "C" void kernel_launch(void* const* d_in, const int* in_sizes, int n_in,
                              void* d_out, int out_size, void* d_ws, size_t ws_size,
                              hipStream_t stream) {
  (void)in_sizes; (void)n_in; (void)d_ws; (void)ws_size; (void)out_size;
  const float* x     = (const float*)d_in[0];
  const float* Winit = (const float*)d_in[1];
  const float* binit = (const float*)d_in[2];
  const float* Wg1   = (const float*)d_in[3];
  const float* bg1   = (const float*)d_in[4];
  const float* Wg2   = (const float*)d_in[5];
  const float* bg2   = (const float*)d_in[6];
  const float* Wfin  = (const float*)d_in[7];
  const float* bfin  = (const float*)d_in[8];
  float* out = (float*)d_out;
  irn_kernel<<<dim3(B_TOTAL/MTILE), dim3(512), 0, stream>>>(
      x, Winit, binit, Wg1, bg1, Wg2, bg2, Wfin, bfin, out);
}